// Round 1
// baseline (385.722 us; speedup 1.0000x reference)
//
#include <hip/hip_runtime.h>

typedef __attribute__((ext_vector_type(8))) short short8;
typedef __attribute__((ext_vector_type(4))) float f32x4;

// Problem constants
// B=4, C=256, pooled spatial 16^3 -> N=4096, kc=vc=128, oc=256

static constexpr size_t OFF_SIGMA = 0;
static constexpr size_t OFF_XF    = 256;
static constexpr size_t OFF_QKT   = OFF_XF  + (size_t)4*256*4096*4;   // f32 xf
static constexpr size_t OFF_V     = OFF_QKT + (size_t)4*4096*128*2;   // bf16 qkT
static constexpr size_t OFF_CTX   = OFF_V   + (size_t)4*128*4096*2;   // bf16 v

__device__ inline unsigned short f2bf(float f) {
  unsigned int u = __float_as_uint(f);
  unsigned int r = u + 0x7fffu + ((u >> 16) & 1u);
  return (unsigned short)(r >> 16);
}

// ---------------- K1: maxpool3d(2): x[4,256,32,32,32] -> xf[4,256,4096] ----
__launch_bounds__(256)
__global__ void k_maxpool(const float* __restrict__ x, float* __restrict__ xf) {
  int idx = blockIdx.x * 256 + threadIdx.x;       // 4*256*4096 total
  int n  = idx & 4095;
  int bc = idx >> 12;
  int d2 = n & 15, d1 = (n >> 4) & 15, d0 = n >> 8;
  const float* p = x + (size_t)bc * 32768 + (size_t)d0 * 2048 + d1 * 64 + d2 * 2;
  float m = fmaxf(p[0], p[1]);
  m = fmaxf(m, fmaxf(p[32], p[33]));
  m = fmaxf(m, fmaxf(p[1024], p[1025]));
  m = fmaxf(m, fmaxf(p[1056], p[1057]));
  xf[idx] = m;
}

// ---------------- K2: spectral-norm sigma = ||W @ normalize(W^T u)|| -------
__global__ void k_sigma(const float* __restrict__ Wk, const float* __restrict__ u,
                        float* __restrict__ sig) {
  __shared__ float vsh[256];
  __shared__ float red[256];
  __shared__ float ush[128];
  int t = threadIdx.x;
  if (t < 128) ush[t] = u[t];
  __syncthreads();
  float acc = 0.f;
  for (int k = 0; k < 128; k++) acc += Wk[(size_t)k * 256 + t] * ush[k];
  vsh[t] = acc;
  red[t] = acc * acc;
  __syncthreads();
  for (int s = 128; s > 0; s >>= 1) { if (t < s) red[t] += red[t + s]; __syncthreads(); }
  float nrm = sqrtf(red[0]) + 1e-12f;
  float vn = vsh[t] / nrm;
  __syncthreads();
  vsh[t] = vn;
  __syncthreads();
  float acc2 = 0.f;
  if (t < 128) {
    for (int c = 0; c < 256; c++) acc2 += Wk[(size_t)t * 256 + c] * vsh[c];
  }
  red[t] = (t < 128) ? acc2 * acc2 : 0.f;
  __syncthreads();
  for (int s = 128; s > 0; s >>= 1) { if (t < s) red[t] += red[t + s]; __syncthreads(); }
  if (t == 0) {
    float s2v = red[0];
    sig[0] = s2v / (sqrtf(s2v) + 1e-12f);
  }
}

// ---------------- K3: fused projections ------------------------------------
// rows 0..127  : qkT[b][n][k] = bf16( (Wk@xf)/sigma + bk )   (layout n-major!)
// rows 128..255: v[b][j][n]   = bf16( Wv@xf + bv )
__launch_bounds__(256)
__global__ void k_qkv(const float* __restrict__ xf,
                      const float* __restrict__ Wk, const float* __restrict__ bk,
                      const float* __restrict__ Wv, const float* __restrict__ bv,
                      const float* __restrict__ sig,
                      unsigned short* __restrict__ qkT, unsigned short* __restrict__ vws) {
  __shared__ float Wl[16][68];   // [c][row], padded: 68*4=272B rows, 16B aligned
  __shared__ float Xl[16][68];   // [c][n]
  int bid = blockIdx.x;
  int ntile = bid & 63, rt = (bid >> 6) & 3, b = bid >> 8;
  int r0 = rt * 64, n0 = ntile * 64;
  int t = threadIdx.x, tx = t & 15, ty = t >> 4;
  float acc[4][4] = {};
  for (int c0 = 0; c0 < 256; c0 += 16) {
#pragma unroll
    for (int i = 0; i < 4; i++) {
      int li = t + i * 256;
      int rr = li >> 4, cc = li & 15;
      int R = r0 + rr;
      Wl[cc][rr] = (R < 128) ? Wk[(size_t)R * 256 + c0 + cc]
                             : Wv[(size_t)(R - 128) * 256 + c0 + cc];
    }
#pragma unroll
    for (int i = 0; i < 4; i++) {
      int li = t + i * 256;
      int nn = li & 63, cc = li >> 6;
      Xl[cc][nn] = xf[((size_t)(b * 256 + c0 + cc)) * 4096 + n0 + nn];
    }
    __syncthreads();
#pragma unroll
    for (int cc = 0; cc < 16; cc++) {
      float4 a4 = *(const float4*)&Wl[cc][ty * 4];
      float4 b4 = *(const float4*)&Xl[cc][tx * 4];
      float av[4] = {a4.x, a4.y, a4.z, a4.w};
      float bvv[4] = {b4.x, b4.y, b4.z, b4.w};
#pragma unroll
      for (int i = 0; i < 4; i++)
#pragma unroll
        for (int j = 0; j < 4; j++) acc[i][j] += av[i] * bvv[j];
    }
    __syncthreads();
  }
  float inv_s = 1.0f / sig[0];
#pragma unroll
  for (int i = 0; i < 4; i++) {
    int R = r0 + ty * 4 + i;
#pragma unroll
    for (int j = 0; j < 4; j++) {
      int n = n0 + tx * 4 + j;
      if (R < 128) {
        float val = acc[i][j] * inv_s + bk[R];
        qkT[((size_t)b * 4096 + n) * 128 + R] = f2bf(val);
      } else {
        float val = acc[i][j] + bv[R - 128];
        vws[((size_t)(b * 128 + (R - 128))) * 4096 + n] = f2bf(val);
      }
    }
  }
}

// ---------------- K4: flash attention --------------------------------------
// grid: 4 batches * 128 q-tiles(32 rows). block: 4 waves.
// wave = (rowg = wid&1 -> 16-row group, mh = wid>>1 -> kv-tile parity split)
// Each wave: online softmax over its 32 kv-tiles of 64 cols; merged at end.
__launch_bounds__(256, 2)
__global__ void k_attn(const unsigned short* __restrict__ qkT,
                       const unsigned short* __restrict__ vws,
                       float* __restrict__ ctx) {
  __shared__ __align__(16) unsigned short plds[4][16][80];  // P tiles, 160B rows
  __shared__ __align__(16) float cmerge[2][16][130];        // merge buffer
  int bid = blockIdx.x;
  int b = bid >> 7;
  int qt = bid & 127;
  int t = threadIdx.x;
  int wid = t >> 6, lane = t & 63;
  int g = lane >> 4, lr = lane & 15;
  int rowg = wid & 1, mh = wid >> 1;
  int qbase = qt * 32 + rowg * 16;
  const unsigned short* qk_b = qkT + (size_t)b * 4096 * 128;
  const unsigned short* v_b  = vws + (size_t)b * 128 * 4096;

  // Q fragments: A[row=lr][k = kk*32 + g*8 + j]
  short8 qf[4];
  {
    const unsigned short* qrow = qk_b + (size_t)(qbase + lr) * 128 + g * 8;
#pragma unroll
    for (int kk = 0; kk < 4; kk++) qf[kk] = *(const short8*)(qrow + kk * 32);
  }
  f32x4 cacc[8];
#pragma unroll
  for (int vf = 0; vf < 8; vf++) cacc[vf] = (f32x4){0.f, 0.f, 0.f, 0.f};
  float m_r[4] = {-INFINITY, -INFINITY, -INFINITY, -INFINITY};
  float l_r[4] = {0.f, 0.f, 0.f, 0.f};

  for (int it = 0; it < 32; ++it) {
    int mbase = (2 * it + mh) * 64;
    f32x4 s[4];
#pragma unroll
    for (int ct = 0; ct < 4; ++ct) {
      f32x4 a = (f32x4){0.f, 0.f, 0.f, 0.f};
      const unsigned short* krow = qk_b + (size_t)(mbase + ct * 16 + lr) * 128 + g * 8;
#pragma unroll
      for (int kk = 0; kk < 4; kk++) {
        short8 kf = *(const short8*)(krow + kk * 32);
        a = __builtin_amdgcn_mfma_f32_16x16x32_bf16(qf[kk], kf, a, 0, 0, 0);
      }
      s[ct] = a * 0.08838834764831845f;  // kc^-0.5
    }
    // online softmax: rows r live in lanes of 16-group g (row = g*4+r)
    float al[4];
#pragma unroll
    for (int r = 0; r < 4; r++) {
      float mx = fmaxf(fmaxf(s[0][r], s[1][r]), fmaxf(s[2][r], s[3][r]));
      mx = fmaxf(mx, __shfl_xor(mx, 1));
      mx = fmaxf(mx, __shfl_xor(mx, 2));
      mx = fmaxf(mx, __shfl_xor(mx, 4));
      mx = fmaxf(mx, __shfl_xor(mx, 8));
      float mn = fmaxf(m_r[r], mx);
      al[r] = __expf(m_r[r] - mn);
      m_r[r] = mn;
    }
    float rs[4] = {0.f, 0.f, 0.f, 0.f};
#pragma unroll
    for (int ct = 0; ct < 4; ++ct)
#pragma unroll
      for (int r = 0; r < 4; r++) {
        float p = __expf(s[ct][r] - m_r[r]);
        s[ct][r] = p;
        rs[r] += p;
      }
#pragma unroll
    for (int r = 0; r < 4; r++) {
      rs[r] += __shfl_xor(rs[r], 1);
      rs[r] += __shfl_xor(rs[r], 2);
      rs[r] += __shfl_xor(rs[r], 4);
      rs[r] += __shfl_xor(rs[r], 8);
      l_r[r] = l_r[r] * al[r] + rs[r];
    }
#pragma unroll
    for (int vf = 0; vf < 8; vf++)
#pragma unroll
      for (int r = 0; r < 4; r++) cacc[vf][r] *= al[r];
    // P -> LDS (C/D layout -> A layout via LDS round trip)
#pragma unroll
    for (int ct = 0; ct < 4; ct++)
#pragma unroll
      for (int r = 0; r < 4; r++)
        plds[wid][g * 4 + r][ct * 16 + lr] = f2bf(s[ct][r]);
    __syncthreads();
#pragma unroll
    for (int kb = 0; kb < 2; kb++) {
      short8 pa = *(const short8*)(&plds[wid][lr][kb * 32 + g * 8]);
#pragma unroll
      for (int vf = 0; vf < 8; vf++) {
        const unsigned short* vptr =
            v_b + (size_t)(vf * 16 + lr) * 4096 + mbase + kb * 32 + g * 8;
        short8 vv = *(const short8*)vptr;
        cacc[vf] = __builtin_amdgcn_mfma_f32_16x16x32_bf16(pa, vv, cacc[vf], 0, 0, 0);
      }
    }
    __syncthreads();
  }

  // merge the two kv-parity halves per 16-row group
  if (mh == 1) {
#pragma unroll
    for (int vf = 0; vf < 8; vf++)
#pragma unroll
      for (int r = 0; r < 4; r++)
        cmerge[rowg][g * 4 + r][vf * 16 + lr] = cacc[vf][r];
    if (lr == 0) {
#pragma unroll
      for (int r = 0; r < 4; r++) {
        cmerge[rowg][g * 4 + r][128] = l_r[r];
        cmerge[rowg][g * 4 + r][129] = m_r[r];
      }
    }
  }
  __syncthreads();
  if (mh == 0) {
#pragma unroll
    for (int r = 0; r < 4; r++) {
      int row = g * 4 + r;
      float l1 = cmerge[rowg][row][128];
      float m1 = cmerge[rowg][row][129];
      float M  = fmaxf(m_r[r], m1);
      float e0 = __expf(m_r[r] - M);
      float e1 = __expf(m1 - M);
      float inv = 1.0f / (l_r[r] * e0 + l1 * e1);
      int n = qbase + row;
      float* crow = ctx + ((size_t)b * 4096 + n) * 128;
#pragma unroll
      for (int vf = 0; vf < 8; vf++) {
        float v1 = cmerge[rowg][row][vf * 16 + lr];
        crow[vf * 16 + lr] = (cacc[vf][r] * e0 + v1 * e1) * inv;
      }
    }
  }
}

// ---------------- K5: output projection out[b,o,n] = Ww@ctx + bw -----------
__launch_bounds__(256)
__global__ void k_out(const float* __restrict__ ctx, const float* __restrict__ Ww,
                      const float* __restrict__ bw, float* __restrict__ out) {
  __shared__ float Wl[16][68];
  __shared__ float Xl[16][68];
  int bid = blockIdx.x;
  int ntile = bid & 63, ot = (bid >> 6) & 3, b = bid >> 8;
  int o0 = ot * 64, n0 = ntile * 64;
  int t = threadIdx.x, tx = t & 15, ty = t >> 4;
  float acc[4][4] = {};
  for (int v0 = 0; v0 < 128; v0 += 16) {
#pragma unroll
    for (int i = 0; i < 4; i++) {
      int li = t + i * 256;
      int rr = li >> 4, cc = li & 15;
      Wl[cc][rr] = Ww[(size_t)(o0 + rr) * 128 + v0 + cc];
    }
#pragma unroll
    for (int i = 0; i < 4; i++) {
      int li = t + i * 256;
      int nn = li >> 4, vv = li & 15;
      Xl[vv][nn] = ctx[((size_t)b * 4096 + n0 + nn) * 128 + v0 + vv];
    }
    __syncthreads();
#pragma unroll
    for (int cc = 0; cc < 16; cc++) {
      float4 a4 = *(const float4*)&Wl[cc][ty * 4];
      float4 b4 = *(const float4*)&Xl[cc][tx * 4];
      float av[4] = {a4.x, a4.y, a4.z, a4.w};
      float bvv[4] = {b4.x, b4.y, b4.z, b4.w};
#pragma unroll
      for (int i = 0; i < 4; i++)
#pragma unroll
        for (int j = 0; j < 4; j++) acc[i][j] += av[i] * bvv[j];
    }
    __syncthreads();
  }
#pragma unroll
  for (int i = 0; i < 4; i++) {
    int o = o0 + ty * 4 + i;
    float bias = bw[o];
#pragma unroll
    for (int j = 0; j < 4; j++) {
      out[((size_t)(b * 256 + o)) * 4096 + n0 + tx * 4 + j] = acc[i][j] + bias;
    }
  }
}

extern "C" void kernel_launch(void* const* d_in, const int* in_sizes, int n_in,
                              void* d_out, int out_size, void* d_ws, size_t ws_size,
                              hipStream_t stream) {
  const float* x  = (const float*)d_in[0];
  const float* Wk = (const float*)d_in[1];
  const float* bk = (const float*)d_in[2];
  const float* Wv = (const float*)d_in[3];
  const float* bv = (const float*)d_in[4];
  const float* Ww = (const float*)d_in[5];
  const float* bw = (const float*)d_in[6];
  const float* u  = (const float*)d_in[7];

  char* ws = (char*)d_ws;
  float* sig            = (float*)(ws + OFF_SIGMA);
  float* xf             = (float*)(ws + OFF_XF);
  unsigned short* qkT   = (unsigned short*)(ws + OFF_QKT);
  unsigned short* vbuf  = (unsigned short*)(ws + OFF_V);
  float* ctx            = (float*)(ws + OFF_CTX);
  float* out            = (float*)d_out;

  k_maxpool<<<16384, 256, 0, stream>>>(x, xf);
  k_sigma<<<1, 256, 0, stream>>>(Wk, u, sig);
  k_qkv<<<1024, 256, 0, stream>>>(xf, Wk, bk, Wv, bv, sig, qkT, vbuf);
  k_attn<<<512, 256, 0, stream>>>(qkT, vbuf, ctx);
  k_out<<<1024, 256, 0, stream>>>(ctx, Ww, bw, out);
}

// Round 2
// 319.827 us; speedup vs baseline: 1.2060x; 1.2060x over previous
//
#include <hip/hip_runtime.h>

typedef __attribute__((ext_vector_type(8))) short short8;
typedef __attribute__((ext_vector_type(4))) float f32x4;

// Problem constants
// B=4, C=256, pooled spatial 16^3 -> N=4096, kc=vc=128, oc=256

static constexpr size_t OFF_SIGMA = 0;
static constexpr size_t OFF_XF    = 256;
static constexpr size_t OFF_QKT   = OFF_XF  + (size_t)4*256*4096*4;   // f32 xf
static constexpr size_t OFF_V     = OFF_QKT + (size_t)4*4096*128*2;   // bf16 qkT
static constexpr size_t OFF_CTX   = OFF_V   + (size_t)4*128*4096*2;   // f32 ctx

__device__ inline unsigned short f2bf(float f) {
  unsigned int u = __float_as_uint(f);
  unsigned int r = u + 0x7fffu + ((u >> 16) & 1u);
  return (unsigned short)(r >> 16);
}

// ---------------- K1: maxpool3d(2): x[4,256,32,32,32] -> xf[4,256,4096] ----
__launch_bounds__(256)
__global__ void k_maxpool(const float* __restrict__ x, float* __restrict__ xf) {
  int idx = blockIdx.x * 256 + threadIdx.x;       // 4*256*4096 total
  int n  = idx & 4095;
  int bc = idx >> 12;
  int d2 = n & 15, d1 = (n >> 4) & 15, d0 = n >> 8;
  const float* p = x + (size_t)bc * 32768 + (size_t)d0 * 2048 + d1 * 64 + d2 * 2;
  float m = fmaxf(p[0], p[1]);
  m = fmaxf(m, fmaxf(p[32], p[33]));
  m = fmaxf(m, fmaxf(p[1024], p[1025]));
  m = fmaxf(m, fmaxf(p[1056], p[1057]));
  xf[idx] = m;
}

// ---------------- K2: spectral-norm sigma = ||W @ normalize(W^T u)|| -------
__global__ void k_sigma(const float* __restrict__ Wk, const float* __restrict__ u,
                        float* __restrict__ sig) {
  __shared__ float vsh[256];
  __shared__ float red[256];
  __shared__ float ush[128];
  int t = threadIdx.x;
  if (t < 128) ush[t] = u[t];
  __syncthreads();
  float acc = 0.f;
  for (int k = 0; k < 128; k++) acc += Wk[(size_t)k * 256 + t] * ush[k];
  vsh[t] = acc;
  red[t] = acc * acc;
  __syncthreads();
  for (int s = 128; s > 0; s >>= 1) { if (t < s) red[t] += red[t + s]; __syncthreads(); }
  float nrm = sqrtf(red[0]) + 1e-12f;
  float vn = vsh[t] / nrm;
  __syncthreads();
  vsh[t] = vn;
  __syncthreads();
  float acc2 = 0.f;
  if (t < 128) {
    for (int c = 0; c < 256; c++) acc2 += Wk[(size_t)t * 256 + c] * vsh[c];
  }
  red[t] = (t < 128) ? acc2 * acc2 : 0.f;
  __syncthreads();
  for (int s = 128; s > 0; s >>= 1) { if (t < s) red[t] += red[t + s]; __syncthreads(); }
  if (t == 0) {
    float s2v = red[0];
    sig[0] = s2v / (sqrtf(s2v) + 1e-12f);
  }
}

// ---------------- K3: fused projections ------------------------------------
// rows 0..127  : qkT[b][n][k] = bf16( (Wk@xf)/sigma + bk )   (layout n-major!)
// rows 128..255: v[b][j][n]   = bf16( Wv@xf + bv )
__launch_bounds__(256)
__global__ void k_qkv(const float* __restrict__ xf,
                      const float* __restrict__ Wk, const float* __restrict__ bk,
                      const float* __restrict__ Wv, const float* __restrict__ bv,
                      const float* __restrict__ sig,
                      unsigned short* __restrict__ qkT, unsigned short* __restrict__ vws) {
  __shared__ float Wl[16][68];   // [c][row]
  __shared__ float Xl[16][68];   // [c][n]
  int bid = blockIdx.x;
  int ntile = bid & 63, rt = (bid >> 6) & 3, b = bid >> 8;
  int r0 = rt * 64, n0 = ntile * 64;
  int t = threadIdx.x, tx = t & 15, ty = t >> 4;
  float acc[4][4] = {};
  for (int c0 = 0; c0 < 256; c0 += 16) {
#pragma unroll
    for (int i = 0; i < 4; i++) {
      int li = t + i * 256;
      int rr = li >> 4, cc = li & 15;
      int R = r0 + rr;
      Wl[cc][rr] = (R < 128) ? Wk[(size_t)R * 256 + c0 + cc]
                             : Wv[(size_t)(R - 128) * 256 + c0 + cc];
    }
#pragma unroll
    for (int i = 0; i < 4; i++) {
      int li = t + i * 256;
      int nn = li & 63, cc = li >> 6;
      Xl[cc][nn] = xf[((size_t)(b * 256 + c0 + cc)) * 4096 + n0 + nn];
    }
    __syncthreads();
#pragma unroll
    for (int cc = 0; cc < 16; cc++) {
      float4 a4 = *(const float4*)&Wl[cc][ty * 4];
      float4 b4 = *(const float4*)&Xl[cc][tx * 4];
      float av[4] = {a4.x, a4.y, a4.z, a4.w};
      float bvv[4] = {b4.x, b4.y, b4.z, b4.w};
#pragma unroll
      for (int i = 0; i < 4; i++)
#pragma unroll
        for (int j = 0; j < 4; j++) acc[i][j] += av[i] * bvv[j];
    }
    __syncthreads();
  }
  float inv_s = 1.0f / sig[0];
#pragma unroll
  for (int i = 0; i < 4; i++) {
    int R = r0 + ty * 4 + i;
#pragma unroll
    for (int j = 0; j < 4; j++) {
      int n = n0 + tx * 4 + j;
      if (R < 128) {
        float val = acc[i][j] * inv_s + bk[R];
        qkT[((size_t)b * 4096 + n) * 128 + R] = f2bf(val);
      } else {
        float val = acc[i][j] + bv[R - 128];
        vws[((size_t)(b * 128 + (R - 128))) * 4096 + n] = f2bf(val);
      }
    }
  }
}

// ---------------- K4: flash attention (barrier-free inner loop) ------------
// grid: 1024 blocks (4 batches * 256 q-tiles of 16 rows), block = 4 waves.
// All 4 waves share the q-tile; wave w handles kv tiles (4*it + w)*64.
// Per-wave LDS arena: P-tile [16][72] ushort, reused as merge buf [16][130] f32.
// One __syncthreads total (before the 4-way merge).
__launch_bounds__(256, 4)
__global__ void k_attn(const unsigned short* __restrict__ qkT,
                       const unsigned short* __restrict__ vws,
                       float* __restrict__ ctx) {
  __shared__ __align__(16) float arena[4][2080];   // 8320 B per wave
  int p = blockIdx.x;
  int bid = (p & 7) * 128 + (p >> 3);              // XCD swizzle (1024 % 8 == 0)
  int b = bid >> 8;
  int qt = bid & 255;
  int t = threadIdx.x;
  int wid = t >> 6, lane = t & 63;
  int g = lane >> 4, lr = lane & 15;
  int qbase = qt * 16;
  const unsigned short* qk_b = qkT + (size_t)b * 4096 * 128;
  const unsigned short* v_b  = vws + (size_t)b * 128 * 4096;
  unsigned short* plds = (unsigned short*)arena[wid];   // [16][72]
  float* cmg = arena[wid];                               // [16][130]

  // Q fragments: A[row=lr][k = kk*32 + g*8 + j]
  short8 qf[4];
  {
    const unsigned short* qrow = qk_b + (size_t)(qbase + lr) * 128 + g * 8;
#pragma unroll
    for (int kk = 0; kk < 4; kk++) qf[kk] = *(const short8*)(qrow + kk * 32);
  }
  f32x4 cacc[8];
#pragma unroll
  for (int vf = 0; vf < 8; vf++) cacc[vf] = (f32x4){0.f, 0.f, 0.f, 0.f};
  float m_r[4] = {-INFINITY, -INFINITY, -INFINITY, -INFINITY};
  float l_r[4] = {0.f, 0.f, 0.f, 0.f};

  for (int it = 0; it < 16; ++it) {
    int mbase = (it * 4 + wid) * 64;
    f32x4 s[4];
    __builtin_amdgcn_s_setprio(1);
#pragma unroll
    for (int ct = 0; ct < 4; ++ct) {
      f32x4 a = (f32x4){0.f, 0.f, 0.f, 0.f};
      const unsigned short* krow = qk_b + (size_t)(mbase + ct * 16 + lr) * 128 + g * 8;
#pragma unroll
      for (int kk = 0; kk < 4; kk++) {
        short8 kf = *(const short8*)(krow + kk * 32);
        a = __builtin_amdgcn_mfma_f32_16x16x32_bf16(qf[kk], kf, a, 0, 0, 0);
      }
      s[ct] = a * 0.08838834764831845f;  // kc^-0.5
    }
    __builtin_amdgcn_s_setprio(0);
    // online softmax: rows r live in lanes of 16-group g (row = g*4+r)
    float al[4];
#pragma unroll
    for (int r = 0; r < 4; r++) {
      float mx = fmaxf(fmaxf(s[0][r], s[1][r]), fmaxf(s[2][r], s[3][r]));
      mx = fmaxf(mx, __shfl_xor(mx, 1));
      mx = fmaxf(mx, __shfl_xor(mx, 2));
      mx = fmaxf(mx, __shfl_xor(mx, 4));
      mx = fmaxf(mx, __shfl_xor(mx, 8));
      float mn = fmaxf(m_r[r], mx);
      al[r] = __expf(m_r[r] - mn);
      m_r[r] = mn;
    }
    float rs[4] = {0.f, 0.f, 0.f, 0.f};
#pragma unroll
    for (int ct = 0; ct < 4; ++ct)
#pragma unroll
      for (int r = 0; r < 4; r++) {
        float pv = __expf(s[ct][r] - m_r[r]);
        s[ct][r] = pv;
        rs[r] += pv;
      }
#pragma unroll
    for (int r = 0; r < 4; r++) {
      rs[r] += __shfl_xor(rs[r], 1);
      rs[r] += __shfl_xor(rs[r], 2);
      rs[r] += __shfl_xor(rs[r], 4);
      rs[r] += __shfl_xor(rs[r], 8);
      l_r[r] = l_r[r] * al[r] + rs[r];
    }
#pragma unroll
    for (int vf = 0; vf < 8; vf++)
#pragma unroll
      for (int r = 0; r < 4; r++) cacc[vf][r] *= al[r];
    // P -> wave-private LDS (C/D layout -> A layout), stride 72 (16B aligned)
#pragma unroll
    for (int ct = 0; ct < 4; ct++)
#pragma unroll
      for (int r = 0; r < 4; r++)
        plds[(g * 4 + r) * 72 + ct * 16 + lr] = f2bf(s[ct][r]);
    __builtin_amdgcn_s_setprio(1);
#pragma unroll
    for (int kb = 0; kb < 2; kb++) {
      short8 pa = *(const short8*)(&plds[lr * 72 + kb * 32 + g * 8]);
#pragma unroll
      for (int vf = 0; vf < 8; vf++) {
        const unsigned short* vptr =
            v_b + (size_t)(vf * 16 + lr) * 4096 + mbase + kb * 32 + g * 8;
        short8 vv = *(const short8*)vptr;
        cacc[vf] = __builtin_amdgcn_mfma_f32_16x16x32_bf16(pa, vv, cacc[vf], 0, 0, 0);
      }
    }
    __builtin_amdgcn_s_setprio(0);
  }

  // dump partials to per-wave merge buffer (reuses P-tile memory; same wave,
  // in-order LDS ops make this safe without a barrier)
#pragma unroll
  for (int vf = 0; vf < 8; vf++)
#pragma unroll
    for (int r = 0; r < 4; r++)
      cmg[(g * 4 + r) * 130 + vf * 16 + lr] = cacc[vf][r];
  if (lr == 0) {
#pragma unroll
    for (int r = 0; r < 4; r++) {
      cmg[(g * 4 + r) * 130 + 128] = m_r[r];
      cmg[(g * 4 + r) * 130 + 129] = l_r[r];
    }
  }
  __syncthreads();

  // 4-way merge: thread t handles row = t>>4, cols (t&15)*8 .. +7
  {
    int row = t >> 4;
    int c0 = (t & 15) * 8;
    float mw[4], lw[4];
#pragma unroll
    for (int w = 0; w < 4; w++) {
      mw[w] = arena[w][row * 130 + 128];
      lw[w] = arena[w][row * 130 + 129];
    }
    float M = fmaxf(fmaxf(mw[0], mw[1]), fmaxf(mw[2], mw[3]));
    float e[4], L = 0.f;
#pragma unroll
    for (int w = 0; w < 4; w++) {
      e[w] = __expf(mw[w] - M);
      L += lw[w] * e[w];
    }
    float inv = 1.0f / L;
    float o[8] = {0.f, 0.f, 0.f, 0.f, 0.f, 0.f, 0.f, 0.f};
#pragma unroll
    for (int w = 0; w < 4; w++)
#pragma unroll
      for (int i = 0; i < 8; i++) o[i] += arena[w][row * 130 + c0 + i] * e[w];
    float* crow = ctx + ((size_t)b * 4096 + qbase + row) * 128 + c0;
#pragma unroll
    for (int i = 0; i < 8; i++) crow[i] = o[i] * inv;
  }
}

// ---------------- K5: output projection out[b,o,n] = Ww@ctx + bw -----------
__launch_bounds__(256)
__global__ void k_out(const float* __restrict__ ctx, const float* __restrict__ Ww,
                      const float* __restrict__ bw, float* __restrict__ out) {
  __shared__ float Wl[16][68];
  __shared__ float Xl[16][68];
  int bid = blockIdx.x;
  int ntile = bid & 63, ot = (bid >> 6) & 3, b = bid >> 8;
  int o0 = ot * 64, n0 = ntile * 64;
  int t = threadIdx.x, tx = t & 15, ty = t >> 4;
  float acc[4][4] = {};
  for (int v0 = 0; v0 < 128; v0 += 16) {
#pragma unroll
    for (int i = 0; i < 4; i++) {
      int li = t + i * 256;
      int rr = li >> 4, cc = li & 15;
      Wl[cc][rr] = Ww[(size_t)(o0 + rr) * 128 + v0 + cc];
    }
#pragma unroll
    for (int i = 0; i < 4; i++) {
      int li = t + i * 256;
      int nn = li >> 4, vv = li & 15;
      Xl[vv][nn] = ctx[((size_t)b * 4096 + n0 + nn) * 128 + v0 + vv];
    }
    __syncthreads();
#pragma unroll
    for (int cc = 0; cc < 16; cc++) {
      float4 a4 = *(const float4*)&Wl[cc][ty * 4];
      float4 b4 = *(const float4*)&Xl[cc][tx * 4];
      float av[4] = {a4.x, a4.y, a4.z, a4.w};
      float bvv[4] = {b4.x, b4.y, b4.z, b4.w};
#pragma unroll
      for (int i = 0; i < 4; i++)
#pragma unroll
        for (int j = 0; j < 4; j++) acc[i][j] += av[i] * bvv[j];
    }
    __syncthreads();
  }
#pragma unroll
  for (int i = 0; i < 4; i++) {
    int o = o0 + ty * 4 + i;
    float bias = bw[o];
#pragma unroll
    for (int j = 0; j < 4; j++) {
      out[((size_t)(b * 256 + o)) * 4096 + n0 + tx * 4 + j] = acc[i][j] + bias;
    }
  }
}

extern "C" void kernel_launch(void* const* d_in, const int* in_sizes, int n_in,
                              void* d_out, int out_size, void* d_ws, size_t ws_size,
                              hipStream_t stream) {
  const float* x  = (const float*)d_in[0];
  const float* Wk = (const float*)d_in[1];
  const float* bk = (const float*)d_in[2];
  const float* Wv = (const float*)d_in[3];
  const float* bv = (const float*)d_in[4];
  const float* Ww = (const float*)d_in[5];
  const float* bw = (const float*)d_in[6];
  const float* u  = (const float*)d_in[7];

  char* ws = (char*)d_ws;
  float* sig            = (float*)(ws + OFF_SIGMA);
  float* xf             = (float*)(ws + OFF_XF);
  unsigned short* qkT   = (unsigned short*)(ws + OFF_QKT);
  unsigned short* vbuf  = (unsigned short*)(ws + OFF_V);
  float* ctx            = (float*)(ws + OFF_CTX);
  float* out            = (float*)d_out;

  k_maxpool<<<16384, 256, 0, stream>>>(x, xf);
  k_sigma<<<1, 256, 0, stream>>>(Wk, u, sig);
  k_qkv<<<1024, 256, 0, stream>>>(xf, Wk, bk, Wv, bv, sig, qkT, vbuf);
  k_attn<<<1024, 256, 0, stream>>>(qkT, vbuf, ctx);
  k_out<<<1024, 256, 0, stream>>>(ctx, Ww, bw, out);
}

// Round 3
// 172.852 us; speedup vs baseline: 2.2315x; 1.8503x over previous
//
#include <hip/hip_runtime.h>

typedef __attribute__((ext_vector_type(8))) short short8;
typedef __attribute__((ext_vector_type(4))) float f32x4;

// B=4, C=256, pooled N=4096, kc=vc=128, oc=256
static constexpr size_t OFF_SIGMA = 0;
static constexpr size_t OFF_ML    = 256;                                // float2[4sp][16384]
static constexpr size_t OFF_QKT   = OFF_ML  + 524288;                   // bf16 [4][4096][128] (swizzled cols)
static constexpr size_t OFF_V     = OFF_QKT + (size_t)4*4096*128*2;     // bf16 [4][128][4096] (swizzled in 64-tiles)
static constexpr size_t OFF_CTX   = OFF_V   + (size_t)4*4096*128*2;     // f32 [4*4096][128]
static constexpr size_t OFF_XF    = OFF_CTX + (size_t)4*4096*128*4;     // f32 [4*256][4096]
static constexpr size_t OFF_PC    = OFF_XF;                             // bf16 [4sp][16384][128] (reuses xf)

__device__ inline unsigned short f2bf(float f) {
  unsigned int u = __float_as_uint(f);
  unsigned int r = u + 0x7fffu + ((u >> 16) & 1u);
  return (unsigned short)(r >> 16);
}
__device__ inline float bf2f(unsigned short s) {
  return __uint_as_float(((unsigned int)s) << 16);
}

// ---------------- K1: maxpool3d(2): x[4,256,32,32,32] -> xf[4,256,4096] ----
__launch_bounds__(256)
__global__ void k_maxpool(const float* __restrict__ x, float* __restrict__ xf) {
  int idx = blockIdx.x * 256 + threadIdx.x;      // 2 outputs per thread
  int n2 = idx & 2047;                           // pair index within 4096
  int bc = idx >> 11;
  int d2p = n2 & 7, d1 = (n2 >> 3) & 15, d0 = n2 >> 7;
  const float* p = x + (size_t)bc * 32768 + (size_t)d0 * 2048 + d1 * 64 + d2p * 4;
  float4 a = *(const float4*)(p);
  float4 b = *(const float4*)(p + 32);
  float4 c = *(const float4*)(p + 1024);
  float4 e = *(const float4*)(p + 1056);
  float o0 = fmaxf(fmaxf(fmaxf(a.x, a.y), fmaxf(b.x, b.y)),
                   fmaxf(fmaxf(c.x, c.y), fmaxf(e.x, e.y)));
  float o1 = fmaxf(fmaxf(fmaxf(a.z, a.w), fmaxf(b.z, b.w)),
                   fmaxf(fmaxf(c.z, c.w), fmaxf(e.z, e.w)));
  *(float2*)(xf + (size_t)bc * 4096 + n2 * 2) = make_float2(o0, o1);
}

// ---------------- K2: spectral-norm sigma ----------------------------------
__global__ void k_sigma(const float* __restrict__ Wk, const float* __restrict__ u,
                        float* __restrict__ sig) {
  __shared__ float vsh[256];
  __shared__ float red[256];
  __shared__ float ush[128];
  int t = threadIdx.x;
  if (t < 128) ush[t] = u[t];
  __syncthreads();
  float acc = 0.f;
  for (int k = 0; k < 128; k++) acc += Wk[(size_t)k * 256 + t] * ush[k];
  vsh[t] = acc;
  red[t] = acc * acc;
  __syncthreads();
  for (int s = 128; s > 0; s >>= 1) { if (t < s) red[t] += red[t + s]; __syncthreads(); }
  float nrm = sqrtf(red[0]) + 1e-12f;
  float vn = vsh[t] / nrm;
  __syncthreads();
  vsh[t] = vn;
  __syncthreads();
  float acc2 = 0.f;
  if (t < 128) {
    for (int c = 0; c < 256; c++) acc2 += Wk[(size_t)t * 256 + c] * vsh[c];
  }
  red[t] = (t < 128) ? acc2 * acc2 : 0.f;
  __syncthreads();
  for (int s = 128; s > 0; s >>= 1) { if (t < s) red[t] += red[t + s]; __syncthreads(); }
  if (t == 0) {
    float s2v = red[0];
    sig[0] = s2v / (sqrtf(s2v) + 1e-12f);
  }
}

// ---------------- K3: fused projections (swizzled stores) ------------------
// K store: qkT[b][n][ ((d>>3)^(n&7))*8 + d&7 ]
// V store: vws[b][d][ n0 + ((c>>3)^(d&7))*8 + c&7 ], c = n&63
__launch_bounds__(256)
__global__ void k_qkv(const float* __restrict__ xf,
                      const float* __restrict__ Wk, const float* __restrict__ bk,
                      const float* __restrict__ Wv, const float* __restrict__ bv,
                      const float* __restrict__ sig,
                      unsigned short* __restrict__ qkT, unsigned short* __restrict__ vws) {
  __shared__ float Wl[16][68];
  __shared__ float Xl[16][68];
  int bid = blockIdx.x;
  int ntile = bid & 63, rt = (bid >> 6) & 3, b = bid >> 8;
  int r0 = rt * 64, n0 = ntile * 64;
  int t = threadIdx.x, tx = t & 15, ty = t >> 4;
  float acc[4][4] = {};
  for (int c0 = 0; c0 < 256; c0 += 16) {
#pragma unroll
    for (int i = 0; i < 4; i++) {
      int li = t + i * 256;
      int rr = li >> 4, cc = li & 15;
      int R = r0 + rr;
      Wl[cc][rr] = (R < 128) ? Wk[(size_t)R * 256 + c0 + cc]
                             : Wv[(size_t)(R - 128) * 256 + c0 + cc];
    }
#pragma unroll
    for (int i = 0; i < 4; i++) {
      int li = t + i * 256;
      int nn = li & 63, cc = li >> 6;
      Xl[cc][nn] = xf[((size_t)(b * 256 + c0 + cc)) * 4096 + n0 + nn];
    }
    __syncthreads();
#pragma unroll
    for (int cc = 0; cc < 16; cc++) {
      float4 a4 = *(const float4*)&Wl[cc][ty * 4];
      float4 b4 = *(const float4*)&Xl[cc][tx * 4];
      float av[4] = {a4.x, a4.y, a4.z, a4.w};
      float bvv[4] = {b4.x, b4.y, b4.z, b4.w};
#pragma unroll
      for (int i = 0; i < 4; i++)
#pragma unroll
        for (int j = 0; j < 4; j++) acc[i][j] += av[i] * bvv[j];
    }
    __syncthreads();
  }
  float inv_s = 1.0f / sig[0];
#pragma unroll
  for (int i = 0; i < 4; i++) {
    int R = r0 + ty * 4 + i;
#pragma unroll
    for (int j = 0; j < 4; j++) {
      int n = n0 + tx * 4 + j;
      if (R < 128) {
        float val = acc[i][j] * inv_s + bk[R];
        int ds = ((((R >> 3) ^ (n & 7)) & 15) << 3) | (R & 7);
        qkT[((size_t)b * 4096 + n) * 128 + ds] = f2bf(val);
      } else {
        int d = R - 128;
        float val = acc[i][j] + bv[d];
        int c = n & 63;
        int cs = ((((c >> 3) ^ (d & 7)) & 7) << 3) | (c & 7);
        vws[((size_t)(b * 128 + d)) * 4096 + n0 + cs] = f2bf(val);
      }
    }
  }
}

// ---------------- K4: flash attention, LDS-staged K/V, 4-way KV split ------
// grid 512 = b(4) x qt(32, 128 q-rows) x sp(4, 1024 kv each). 4 waves/block,
// wave owns 32 q-rows (2 row-frags). K/V tile 64kv staged in LDS per iter,
// reg double-buffered (T14). Writes bf16 partials + (m,l) per row.
__launch_bounds__(256, 2)
__global__ void k_attn(const unsigned short* __restrict__ qkT,
                       const unsigned short* __restrict__ vws,
                       unsigned short* __restrict__ pc, float2* __restrict__ ml) {
  __shared__ __align__(16) char smem[32768 + 4 * 4608];  // K 16K | V 16K | P 4x4.5K
  int p = blockIdx.x;
  int bid = (p & 7) * 64 + (p >> 3);                     // XCD swizzle (512%8==0)
  int sp = bid & 3, qt = (bid >> 2) & 31, b = bid >> 7;
  int t = threadIdx.x, wid = t >> 6, lane = t & 63, g = lane >> 4, lr = lane & 15;
  int qrb = qt * 128 + wid * 32;
  const unsigned short* qk_b = qkT + (size_t)b * 524288;
  const char* kgb = (const char*)qk_b;
  const char* vgb = (const char*)(vws + (size_t)b * 524288);
  char* KL = smem;
  char* VL = smem + 16384;
  unsigned short* PL = (unsigned short*)(smem + 32768 + wid * 4608);  // [32][72]

  // Q fragments (unswizzle the stored K layout)
  short8 qf[2][4];
#pragma unroll
  for (int rt = 0; rt < 2; rt++)
#pragma unroll
    for (int kk = 0; kk < 4; kk++) {
      int row = qrb + rt * 16 + lr;
      qf[rt][kk] = *(const short8*)(qk_b + (size_t)row * 128 +
                                    ((((kk * 4 + g) ^ (lr & 7)) & 15) << 3));
    }

  f32x4 cacc[2][8];
#pragma unroll
  for (int rt = 0; rt < 2; rt++)
#pragma unroll
    for (int vt = 0; vt < 8; vt++) cacc[rt][vt] = (f32x4){0.f, 0.f, 0.f, 0.f};
  f32x4 m0 = {-INFINITY, -INFINITY, -INFINITY, -INFINITY}, m1 = m0;
  f32x4 l0 = {0.f, 0.f, 0.f, 0.f}, l1 = l0;

  int drow = t >> 3;            // V stage: row within 32-row chunk
  int cb   = (t & 7) * 16;      // byte col within 128B row

  // prologue: stage regs for it=0
  short8 kst[4], vst[4];
  {
    int mb = sp * 1024;
    const char* kg = kgb + (size_t)mb * 256;
#pragma unroll
    for (int i = 0; i < 4; i++) kst[i] = *(const short8*)(kg + i * 4096 + t * 16);
#pragma unroll
    for (int i = 0; i < 4; i++)
      vst[i] = *(const short8*)(vgb + (size_t)(i * 32 + drow) * 8192 + mb * 2 + cb);
  }

#pragma unroll 1
  for (int it = 0; it < 16; ++it) {
    int mbase = sp * 1024 + it * 64;
    __syncthreads();   // previous compute done; tiles free
#pragma unroll
    for (int i = 0; i < 4; i++) *(short8*)(KL + i * 4096 + t * 16) = kst[i];
#pragma unroll
    for (int i = 0; i < 4; i++) *(short8*)(VL + i * 4096 + t * 16) = vst[i];
    if (it < 15) {    // issue next tile's global loads (hide under compute)
      int mb = mbase + 64;
      const char* kg = kgb + (size_t)mb * 256;
#pragma unroll
      for (int i = 0; i < 4; i++) kst[i] = *(const short8*)(kg + i * 4096 + t * 16);
#pragma unroll
      for (int i = 0; i < 4; i++)
        vst[i] = *(const short8*)(vgb + (size_t)(i * 32 + drow) * 8192 + mb * 2 + cb);
    }
    __syncthreads();   // tiles ready

    // ---- QK^T: 32 q-rows x 64 kv ----
    const float scl = 0.08838834764831845f;
    f32x4 s0[4], s1[4];
#pragma unroll
    for (int ct = 0; ct < 4; ct++) {
      short8 kf[4];
#pragma unroll
      for (int kk = 0; kk < 4; kk++)
        kf[kk] = *(const short8*)(KL + (ct * 16 + lr) * 256 +
                                  ((((kk * 4 + g) ^ (lr & 7)) & 15) << 4));
      f32x4 a0 = {0.f, 0.f, 0.f, 0.f}, a1 = a0;
#pragma unroll
      for (int kk = 0; kk < 4; kk++) {
        a0 = __builtin_amdgcn_mfma_f32_16x16x32_bf16(qf[0][kk], kf[kk], a0, 0, 0, 0);
        a1 = __builtin_amdgcn_mfma_f32_16x16x32_bf16(qf[1][kk], kf[kk], a1, 0, 0, 0);
      }
      s0[ct] = a0 * scl;
      s1[ct] = a1 * scl;
    }

    // ---- online softmax rt=0 ----
    f32x4 al0, al1;
#pragma unroll
    for (int r = 0; r < 4; r++) {
      float mx = fmaxf(fmaxf(s0[0][r], s0[1][r]), fmaxf(s0[2][r], s0[3][r]));
      mx = fmaxf(mx, __shfl_xor(mx, 1));
      mx = fmaxf(mx, __shfl_xor(mx, 2));
      mx = fmaxf(mx, __shfl_xor(mx, 4));
      mx = fmaxf(mx, __shfl_xor(mx, 8));
      float mn = fmaxf(m0[r], mx);
      al0[r] = __expf(m0[r] - mn);
      m0[r] = mn;
    }
    f32x4 rs0 = {0.f, 0.f, 0.f, 0.f};
#pragma unroll
    for (int ct = 0; ct < 4; ct++)
#pragma unroll
      for (int r = 0; r < 4; r++) {
        float pv = __expf(s0[ct][r] - m0[r]);
        s0[ct][r] = pv;
        rs0[r] += pv;
      }
#pragma unroll
    for (int r = 0; r < 4; r++) {
      float v = rs0[r];
      v += __shfl_xor(v, 1); v += __shfl_xor(v, 2);
      v += __shfl_xor(v, 4); v += __shfl_xor(v, 8);
      l0[r] = l0[r] * al0[r] + v;
    }
    // ---- online softmax rt=1 ----
#pragma unroll
    for (int r = 0; r < 4; r++) {
      float mx = fmaxf(fmaxf(s1[0][r], s1[1][r]), fmaxf(s1[2][r], s1[3][r]));
      mx = fmaxf(mx, __shfl_xor(mx, 1));
      mx = fmaxf(mx, __shfl_xor(mx, 2));
      mx = fmaxf(mx, __shfl_xor(mx, 4));
      mx = fmaxf(mx, __shfl_xor(mx, 8));
      float mn = fmaxf(m1[r], mx);
      al1[r] = __expf(m1[r] - mn);
      m1[r] = mn;
    }
    f32x4 rs1 = {0.f, 0.f, 0.f, 0.f};
#pragma unroll
    for (int ct = 0; ct < 4; ct++)
#pragma unroll
      for (int r = 0; r < 4; r++) {
        float pv = __expf(s1[ct][r] - m1[r]);
        s1[ct][r] = pv;
        rs1[r] += pv;
      }
#pragma unroll
    for (int r = 0; r < 4; r++) {
      float v = rs1[r];
      v += __shfl_xor(v, 1); v += __shfl_xor(v, 2);
      v += __shfl_xor(v, 4); v += __shfl_xor(v, 8);
      l1[r] = l1[r] * al1[r] + v;
    }
    // rescale accumulators
#pragma unroll
    for (int vt = 0; vt < 8; vt++) { cacc[0][vt] *= al0; cacc[1][vt] *= al1; }
    // P -> wave-private LDS [32][72]
#pragma unroll
    for (int ct = 0; ct < 4; ct++)
#pragma unroll
      for (int r = 0; r < 4; r++) {
        PL[(g * 4 + r) * 72 + ct * 16 + lr]      = f2bf(s0[ct][r]);
        PL[(16 + g * 4 + r) * 72 + ct * 16 + lr] = f2bf(s1[ct][r]);
      }

    // ---- PV ----
#pragma unroll
    for (int ks = 0; ks < 2; ks++) {
      short8 pa0 = *(const short8*)(PL + lr * 72 + ks * 32 + g * 8);
      short8 pa1 = *(const short8*)(PL + (16 + lr) * 72 + ks * 32 + g * 8);
#pragma unroll
      for (int vt = 0; vt < 8; vt++) {
        short8 vb = *(const short8*)(VL + (vt * 16 + lr) * 128 +
                                     ((((ks * 4 + g) ^ (lr & 7)) & 7) << 4));
        cacc[0][vt] = __builtin_amdgcn_mfma_f32_16x16x32_bf16(pa0, vb, cacc[0][vt], 0, 0, 0);
        cacc[1][vt] = __builtin_amdgcn_mfma_f32_16x16x32_bf16(pa1, vb, cacc[1][vt], 0, 0, 0);
      }
    }
  }

  // ---- epilogue: bf16 partials + (m,l) ----
#pragma unroll
  for (int rt = 0; rt < 2; rt++)
#pragma unroll
    for (int vt = 0; vt < 8; vt++)
#pragma unroll
      for (int r = 0; r < 4; r++) {
        int n = qrb + rt * 16 + g * 4 + r;
        size_t gn = (size_t)b * 4096 + n;
        float v = rt ? cacc[1][vt][r] : cacc[0][vt][r];
        pc[((size_t)sp * 16384 + gn) * 128 + vt * 16 + lr] = f2bf(v);
      }
  if (lr == 0) {
#pragma unroll
    for (int rt = 0; rt < 2; rt++)
#pragma unroll
      for (int r = 0; r < 4; r++) {
        int n = qrb + rt * 16 + g * 4 + r;
        size_t gn = (size_t)b * 4096 + n;
        float mm = rt ? m1[r] : m0[r];
        float ll = rt ? l1[r] : l0[r];
        ml[sp * 16384 + gn] = make_float2(mm, ll);
      }
  }
}

// ---------------- K4b: merge 4 KV-split partials -> ctx (f32) --------------
__launch_bounds__(256)
__global__ void k_merge(const unsigned short* __restrict__ pc,
                        const float2* __restrict__ ml, float* __restrict__ ctx) {
  int idx = blockIdx.x * 256 + threadIdx.x;   // 16 threads per row
  int gn = idx >> 4;
  int c8 = (idx & 15) * 8;
  float m[4], l[4];
#pragma unroll
  for (int sp = 0; sp < 4; sp++) {
    float2 v = ml[sp * 16384 + gn];
    m[sp] = v.x; l[sp] = v.y;
  }
  float M = fmaxf(fmaxf(m[0], m[1]), fmaxf(m[2], m[3]));
  float e[4], L = 0.f;
#pragma unroll
  for (int sp = 0; sp < 4; sp++) { e[sp] = __expf(m[sp] - M); L += l[sp] * e[sp]; }
  float inv = 1.0f / L;
  float o[8] = {};
#pragma unroll
  for (int sp = 0; sp < 4; sp++) {
    short8 pv = *(const short8*)(pc + ((size_t)sp * 16384 + gn) * 128 + c8);
#pragma unroll
    for (int j = 0; j < 8; j++) o[j] += e[sp] * bf2f((unsigned short)pv[j]);
  }
  float4 o0 = make_float4(o[0] * inv, o[1] * inv, o[2] * inv, o[3] * inv);
  float4 o1 = make_float4(o[4] * inv, o[5] * inv, o[6] * inv, o[7] * inv);
  *(float4*)(ctx + (size_t)gn * 128 + c8) = o0;
  *(float4*)(ctx + (size_t)gn * 128 + c8 + 4) = o1;
}

// ---------------- K5: output projection out[b,o,n] = Ww@ctx + bw -----------
__launch_bounds__(256)
__global__ void k_out(const float* __restrict__ ctx, const float* __restrict__ Ww,
                      const float* __restrict__ bw, float* __restrict__ out) {
  __shared__ float Wl[16][68];
  __shared__ float Xl[16][68];
  int bid = blockIdx.x;
  int ntile = bid & 63, ot = (bid >> 6) & 3, b = bid >> 8;
  int o0 = ot * 64, n0 = ntile * 64;
  int t = threadIdx.x, tx = t & 15, ty = t >> 4;
  float acc[4][4] = {};
  for (int v0 = 0; v0 < 128; v0 += 16) {
#pragma unroll
    for (int i = 0; i < 4; i++) {
      int li = t + i * 256;
      int rr = li >> 4, cc = li & 15;
      Wl[cc][rr] = Ww[(size_t)(o0 + rr) * 128 + v0 + cc];
    }
#pragma unroll
    for (int i = 0; i < 4; i++) {
      int li = t + i * 256;
      int nn = li >> 4, vv = li & 15;
      Xl[vv][nn] = ctx[((size_t)b * 4096 + n0 + nn) * 128 + v0 + vv];
    }
    __syncthreads();
#pragma unroll
    for (int cc = 0; cc < 16; cc++) {
      float4 a4 = *(const float4*)&Wl[cc][ty * 4];
      float4 b4 = *(const float4*)&Xl[cc][tx * 4];
      float av[4] = {a4.x, a4.y, a4.z, a4.w};
      float bvv[4] = {b4.x, b4.y, b4.z, b4.w};
#pragma unroll
      for (int i = 0; i < 4; i++)
#pragma unroll
        for (int j = 0; j < 4; j++) acc[i][j] += av[i] * bvv[j];
    }
    __syncthreads();
  }
#pragma unroll
  for (int i = 0; i < 4; i++) {
    int o = o0 + ty * 4 + i;
    float bias = bw[o];
#pragma unroll
    for (int j = 0; j < 4; j++) {
      out[((size_t)(b * 256 + o)) * 4096 + n0 + tx * 4 + j] = acc[i][j] + bias;
    }
  }
}

extern "C" void kernel_launch(void* const* d_in, const int* in_sizes, int n_in,
                              void* d_out, int out_size, void* d_ws, size_t ws_size,
                              hipStream_t stream) {
  const float* x  = (const float*)d_in[0];
  const float* Wk = (const float*)d_in[1];
  const float* bk = (const float*)d_in[2];
  const float* Wv = (const float*)d_in[3];
  const float* bv = (const float*)d_in[4];
  const float* Ww = (const float*)d_in[5];
  const float* bw = (const float*)d_in[6];
  const float* u  = (const float*)d_in[7];

  char* ws = (char*)d_ws;
  float* sig            = (float*)(ws + OFF_SIGMA);
  float2* ml            = (float2*)(ws + OFF_ML);
  unsigned short* qkT   = (unsigned short*)(ws + OFF_QKT);
  unsigned short* vbuf  = (unsigned short*)(ws + OFF_V);
  float* ctx            = (float*)(ws + OFF_CTX);
  float* xf             = (float*)(ws + OFF_XF);
  unsigned short* pc    = (unsigned short*)(ws + OFF_PC);
  float* out            = (float*)d_out;

  k_maxpool<<<8192, 256, 0, stream>>>(x, xf);
  k_sigma<<<1, 256, 0, stream>>>(Wk, u, sig);
  k_qkv<<<1024, 256, 0, stream>>>(xf, Wk, bk, Wv, bv, sig, qkT, vbuf);
  k_attn<<<512, 256, 0, stream>>>(qkT, vbuf, pc, ml);
  k_merge<<<1024, 256, 0, stream>>>(pc, ml, ctx);
  k_out<<<1024, 256, 0, stream>>>(ctx, Ww, bw, out);
}

// Round 4
// 160.765 us; speedup vs baseline: 2.3993x; 1.0752x over previous
//
#include <hip/hip_runtime.h>

typedef __attribute__((ext_vector_type(8))) short short8;
typedef __attribute__((ext_vector_type(4))) float f32x4;

// B=4, C=256, pooled N=4096, kc=vc=128, oc=256
static constexpr size_t OFF_SIGMA = 0;
static constexpr size_t OFF_ML    = 256;                                 // float2[8sp][16384]
static constexpr size_t OFF_QKT   = OFF_ML + 1048576;                    // bf16 [4][4096][128] (swizzled cols)
static constexpr size_t OFF_V     = OFF_QKT + (size_t)4*4096*128*2;      // bf16 [4][128][4096] (swizzled 64-tiles)
static constexpr size_t OFF_WWB   = OFF_V + (size_t)4*4096*128*2;        // bf16 [256][128]
static constexpr size_t OFF_XF    = OFF_WWB + 65536;                     // f32 [4*256][4096]
static constexpr size_t OFF_PC    = OFF_XF;                              // bf16 [nsp][16384][128] (reuses xf)
static constexpr size_t NEED8     = OFF_PC + (size_t)8*16384*128*2;      // ~43 MB

__device__ inline unsigned short f2bf(float f) {
  unsigned int u = __float_as_uint(f);
  unsigned int r = u + 0x7fffu + ((u >> 16) & 1u);
  return (unsigned short)(r >> 16);
}
__device__ inline float bf2f(unsigned short s) {
  return __uint_as_float(((unsigned int)s) << 16);
}

// ---------------- K1: maxpool3d(2): x[4,256,32,32,32] -> xf[4,256,4096] ----
__launch_bounds__(256)
__global__ void k_maxpool(const float* __restrict__ x, float* __restrict__ xf) {
  int idx = blockIdx.x * 256 + threadIdx.x;      // 2 outputs per thread
  int n2 = idx & 2047;
  int bc = idx >> 11;
  int d2p = n2 & 7, d1 = (n2 >> 3) & 15, d0 = n2 >> 7;
  const float* p = x + (size_t)bc * 32768 + (size_t)d0 * 2048 + d1 * 64 + d2p * 4;
  float4 a = *(const float4*)(p);
  float4 b = *(const float4*)(p + 32);
  float4 c = *(const float4*)(p + 1024);
  float4 e = *(const float4*)(p + 1056);
  float o0 = fmaxf(fmaxf(fmaxf(a.x, a.y), fmaxf(b.x, b.y)),
                   fmaxf(fmaxf(c.x, c.y), fmaxf(e.x, e.y)));
  float o1 = fmaxf(fmaxf(fmaxf(a.z, a.w), fmaxf(b.z, b.w)),
                   fmaxf(fmaxf(c.z, c.w), fmaxf(e.z, e.w)));
  *(float2*)(xf + (size_t)bc * 4096 + n2 * 2) = make_float2(o0, o1);
}

// ---------------- K2: spectral-norm sigma ----------------------------------
__global__ void k_sigma(const float* __restrict__ Wk, const float* __restrict__ u,
                        float* __restrict__ sig) {
  __shared__ float vsh[256];
  __shared__ float red[256];
  __shared__ float ush[128];
  int t = threadIdx.x;
  if (t < 128) ush[t] = u[t];
  __syncthreads();
  float acc = 0.f;
  for (int k = 0; k < 128; k++) acc += Wk[(size_t)k * 256 + t] * ush[k];
  vsh[t] = acc;
  red[t] = acc * acc;
  __syncthreads();
  for (int s = 128; s > 0; s >>= 1) { if (t < s) red[t] += red[t + s]; __syncthreads(); }
  float nrm = sqrtf(red[0]) + 1e-12f;
  float vn = vsh[t] / nrm;
  __syncthreads();
  vsh[t] = vn;
  __syncthreads();
  float acc2 = 0.f;
  if (t < 128) {
    for (int c = 0; c < 256; c++) acc2 += Wk[(size_t)t * 256 + c] * vsh[c];
  }
  red[t] = (t < 128) ? acc2 * acc2 : 0.f;
  __syncthreads();
  for (int s = 128; s > 0; s >>= 1) { if (t < s) red[t] += red[t + s]; __syncthreads(); }
  if (t == 0) {
    float s2v = red[0];
    sig[0] = s2v / (sqrtf(s2v) + 1e-12f);
  }
}

// ---------------- K2b: Ww f32 -> bf16 --------------------------------------
__launch_bounds__(256)
__global__ void k_prep(const float* __restrict__ Ww, unsigned short* __restrict__ wwb) {
  int i = (blockIdx.x * 256 + threadIdx.x) * 4;       // 32768 total
  float4 w = *(const float4*)(Ww + i);
  unsigned int lo = (unsigned int)f2bf(w.x) | ((unsigned int)f2bf(w.y) << 16);
  unsigned int hi = (unsigned int)f2bf(w.z) | ((unsigned int)f2bf(w.w) << 16);
  *(uint2*)(wwb + i) = make_uint2(lo, hi);
}

// ---------------- K3: fused projections (swizzled stores) ------------------
__launch_bounds__(256)
__global__ void k_qkv(const float* __restrict__ xf,
                      const float* __restrict__ Wk, const float* __restrict__ bk,
                      const float* __restrict__ Wv, const float* __restrict__ bv,
                      const float* __restrict__ sig,
                      unsigned short* __restrict__ qkT, unsigned short* __restrict__ vws) {
  __shared__ float Wl[16][68];
  __shared__ float Xl[16][68];
  int bid = blockIdx.x;
  int ntile = bid & 63, rt = (bid >> 6) & 3, b = bid >> 8;
  int r0 = rt * 64, n0 = ntile * 64;
  int t = threadIdx.x, tx = t & 15, ty = t >> 4;
  float acc[4][4] = {};
  for (int c0 = 0; c0 < 256; c0 += 16) {
#pragma unroll
    for (int i = 0; i < 4; i++) {
      int li = t + i * 256;
      int rr = li >> 4, cc = li & 15;
      int R = r0 + rr;
      Wl[cc][rr] = (R < 128) ? Wk[(size_t)R * 256 + c0 + cc]
                             : Wv[(size_t)(R - 128) * 256 + c0 + cc];
    }
#pragma unroll
    for (int i = 0; i < 4; i++) {
      int li = t + i * 256;
      int nn = li & 63, cc = li >> 6;
      Xl[cc][nn] = xf[((size_t)(b * 256 + c0 + cc)) * 4096 + n0 + nn];
    }
    __syncthreads();
#pragma unroll
    for (int cc = 0; cc < 16; cc++) {
      float4 a4 = *(const float4*)&Wl[cc][ty * 4];
      float4 b4 = *(const float4*)&Xl[cc][tx * 4];
      float av[4] = {a4.x, a4.y, a4.z, a4.w};
      float bvv[4] = {b4.x, b4.y, b4.z, b4.w};
#pragma unroll
      for (int i = 0; i < 4; i++)
#pragma unroll
        for (int j = 0; j < 4; j++) acc[i][j] += av[i] * bvv[j];
    }
    __syncthreads();
  }
  float inv_s = 1.0f / sig[0];
#pragma unroll
  for (int i = 0; i < 4; i++) {
    int R = r0 + ty * 4 + i;
#pragma unroll
    for (int j = 0; j < 4; j++) {
      int n = n0 + tx * 4 + j;
      if (R < 128) {
        float val = acc[i][j] * inv_s + bk[R];
        int ds = ((((R >> 3) ^ (n & 7)) & 15) << 3) | (R & 7);
        qkT[((size_t)b * 4096 + n) * 128 + ds] = f2bf(val);
      } else {
        int d = R - 128;
        float val = acc[i][j] + bv[d];
        int c = n & 63;
        int cs = ((((c >> 3) ^ (d & 7)) & 7) << 3) | (c & 7);
        vws[((size_t)(b * 128 + d)) * 4096 + n0 + cs] = f2bf(val);
      }
    }
  }
}

// ---------------- K4: flash attention --------------------------------------
// grid 128*nsp = b(4) x qt(32, 128 q-rows) x sp(nsp). 4 waves, 32 q-rows/wave.
// exp2-folded scale, defer-max, LDS-staged K/V double-buffered via regs.
__launch_bounds__(256, 2)
__global__ void k_attn(const unsigned short* __restrict__ qkT,
                       const unsigned short* __restrict__ vws,
                       unsigned short* __restrict__ pc, float2* __restrict__ ml,
                       int nsp, int spbits) {
  __shared__ __align__(16) char smem[32768 + 4 * 4608];  // K 16K | V 16K | P 4x4.5K
  const float C1 = 0.12754245f;        // (1/sqrt(128)) * log2(e)
  const float RAW_THR = 62.72f;        // 8 / C1
  int nwg = gridDim.x;
  int p = blockIdx.x;
  int bid = (p & 7) * (nwg >> 3) + (p >> 3);             // XCD swizzle
  int sp = bid & (nsp - 1);
  int qt = (bid >> spbits) & 31;
  int b = bid >> (spbits + 5);
  int iters = 64 >> spbits;                              // 16 or 8
  int kv0 = sp << (12 - spbits);
  int t = threadIdx.x, wid = t >> 6, lane = t & 63, g = lane >> 4, lr = lane & 15;
  int qrb = qt * 128 + wid * 32;
  const unsigned short* qk_b = qkT + (size_t)b * 524288;
  const char* kgb = (const char*)qk_b;
  const char* vgb = (const char*)(vws + (size_t)b * 524288);
  char* KL = smem;
  char* VL = smem + 16384;
  unsigned short* PL = (unsigned short*)(smem + 32768 + wid * 4608);  // [32][72]

  // Q fragments (unswizzle stored layout)
  short8 qf[2][4];
#pragma unroll
  for (int rt = 0; rt < 2; rt++)
#pragma unroll
    for (int kk = 0; kk < 4; kk++) {
      int row = qrb + rt * 16 + lr;
      qf[rt][kk] = *(const short8*)(qk_b + (size_t)row * 128 +
                                    ((((kk * 4 + g) ^ (lr & 7)) & 15) << 3));
    }

  f32x4 cacc[2][8];
#pragma unroll
  for (int rt = 0; rt < 2; rt++)
#pragma unroll
    for (int vt = 0; vt < 8; vt++) cacc[rt][vt] = (f32x4){0.f, 0.f, 0.f, 0.f};
  float m0[4] = {-INFINITY, -INFINITY, -INFINITY, -INFINITY};
  float m1[4] = {-INFINITY, -INFINITY, -INFINITY, -INFINITY};
  float mc0[4] = {-INFINITY, -INFINITY, -INFINITY, -INFINITY};
  float mc1[4] = {-INFINITY, -INFINITY, -INFINITY, -INFINITY};
  float l0[4] = {0.f, 0.f, 0.f, 0.f}, l1[4] = {0.f, 0.f, 0.f, 0.f};

  int drow = t >> 3;
  int cb   = (t & 7) * 16;

  short8 kst[4], vst[4];
  {
    const char* kg = kgb + (size_t)kv0 * 256;
#pragma unroll
    for (int i = 0; i < 4; i++) kst[i] = *(const short8*)(kg + i * 4096 + t * 16);
#pragma unroll
    for (int i = 0; i < 4; i++)
      vst[i] = *(const short8*)(vgb + (size_t)(i * 32 + drow) * 8192 + kv0 * 2 + cb);
  }

#pragma unroll 1
  for (int it = 0; it < iters; ++it) {
    int mbase = kv0 + it * 64;
    __syncthreads();
#pragma unroll
    for (int i = 0; i < 4; i++) *(short8*)(KL + i * 4096 + t * 16) = kst[i];
#pragma unroll
    for (int i = 0; i < 4; i++) *(short8*)(VL + i * 4096 + t * 16) = vst[i];
    if (it < iters - 1) {
      int mb = mbase + 64;
      const char* kg = kgb + (size_t)mb * 256;
#pragma unroll
      for (int i = 0; i < 4; i++) kst[i] = *(const short8*)(kg + i * 4096 + t * 16);
#pragma unroll
      for (int i = 0; i < 4; i++)
        vst[i] = *(const short8*)(vgb + (size_t)(i * 32 + drow) * 8192 + mb * 2 + cb);
    }
    __syncthreads();

    // ---- QK^T (raw scores; scale folded into exp2) ----
    f32x4 s0[4], s1[4];
    __builtin_amdgcn_s_setprio(1);
#pragma unroll
    for (int ct = 0; ct < 4; ct++) {
      short8 kf[4];
#pragma unroll
      for (int kk = 0; kk < 4; kk++)
        kf[kk] = *(const short8*)(KL + (ct * 16 + lr) * 256 +
                                  ((((kk * 4 + g) ^ (lr & 7)) & 15) << 4));
      f32x4 a0 = {0.f, 0.f, 0.f, 0.f}, a1 = a0;
#pragma unroll
      for (int kk = 0; kk < 4; kk++) {
        a0 = __builtin_amdgcn_mfma_f32_16x16x32_bf16(qf[0][kk], kf[kk], a0, 0, 0, 0);
        a1 = __builtin_amdgcn_mfma_f32_16x16x32_bf16(qf[1][kk], kf[kk], a1, 0, 0, 0);
      }
      s0[ct] = a0;
      s1[ct] = a1;
    }
    __builtin_amdgcn_s_setprio(0);

    // ---- online softmax (defer-max, exp2) ----
    float mx0[4], mx1[4];
#pragma unroll
    for (int r = 0; r < 4; r++) {
      float mx = fmaxf(fmaxf(s0[0][r], s0[1][r]), fmaxf(s0[2][r], s0[3][r]));
      mx = fmaxf(mx, __shfl_xor(mx, 1));
      mx = fmaxf(mx, __shfl_xor(mx, 2));
      mx = fmaxf(mx, __shfl_xor(mx, 4));
      mx = fmaxf(mx, __shfl_xor(mx, 8));
      mx0[r] = mx;
      float my = fmaxf(fmaxf(s1[0][r], s1[1][r]), fmaxf(s1[2][r], s1[3][r]));
      my = fmaxf(my, __shfl_xor(my, 1));
      my = fmaxf(my, __shfl_xor(my, 2));
      my = fmaxf(my, __shfl_xor(my, 4));
      my = fmaxf(my, __shfl_xor(my, 8));
      mx1[r] = my;
    }
    bool need = false;
#pragma unroll
    for (int r = 0; r < 4; r++)
      need = need || (mx0[r] > m0[r] + RAW_THR) || (mx1[r] > m1[r] + RAW_THR);
    if (__any(need)) {
#pragma unroll
      for (int r = 0; r < 4; r++) {
        float mn0 = fmaxf(m0[r], mx0[r]);
        float al0 = __builtin_amdgcn_exp2f((m0[r] - mn0) * C1);
        m0[r] = mn0; mc0[r] = mn0 * C1;
        l0[r] *= al0;
        float mn1 = fmaxf(m1[r], mx1[r]);
        float al1 = __builtin_amdgcn_exp2f((m1[r] - mn1) * C1);
        m1[r] = mn1; mc1[r] = mn1 * C1;
        l1[r] *= al1;
#pragma unroll
        for (int vt = 0; vt < 8; vt++) { cacc[0][vt][r] *= al0; cacc[1][vt][r] *= al1; }
      }
    }
    float rs0[4] = {0.f, 0.f, 0.f, 0.f}, rs1[4] = {0.f, 0.f, 0.f, 0.f};
#pragma unroll
    for (int ct = 0; ct < 4; ct++)
#pragma unroll
      for (int r = 0; r < 4; r++) {
        float p0 = __builtin_amdgcn_exp2f(fmaf(s0[ct][r], C1, -mc0[r]));
        float p1 = __builtin_amdgcn_exp2f(fmaf(s1[ct][r], C1, -mc1[r]));
        s0[ct][r] = p0; rs0[r] += p0;
        s1[ct][r] = p1; rs1[r] += p1;
      }
#pragma unroll
    for (int r = 0; r < 4; r++) {
      float v = rs0[r];
      v += __shfl_xor(v, 1); v += __shfl_xor(v, 2);
      v += __shfl_xor(v, 4); v += __shfl_xor(v, 8);
      l0[r] += v;
      float w = rs1[r];
      w += __shfl_xor(w, 1); w += __shfl_xor(w, 2);
      w += __shfl_xor(w, 4); w += __shfl_xor(w, 8);
      l1[r] += w;
    }
    // P -> wave-private LDS [32][72] (half-up bf16 round: 2 ops)
#pragma unroll
    for (int ct = 0; ct < 4; ct++)
#pragma unroll
      for (int r = 0; r < 4; r++) {
        PL[(g * 4 + r) * 72 + ct * 16 + lr] =
            (unsigned short)((__float_as_uint(s0[ct][r]) + 0x8000u) >> 16);
        PL[(16 + g * 4 + r) * 72 + ct * 16 + lr] =
            (unsigned short)((__float_as_uint(s1[ct][r]) + 0x8000u) >> 16);
      }

    // ---- PV ----
    __builtin_amdgcn_s_setprio(1);
#pragma unroll
    for (int ks = 0; ks < 2; ks++) {
      short8 pa0 = *(const short8*)(PL + lr * 72 + ks * 32 + g * 8);
      short8 pa1 = *(const short8*)(PL + (16 + lr) * 72 + ks * 32 + g * 8);
#pragma unroll
      for (int vt = 0; vt < 8; vt++) {
        short8 vb = *(const short8*)(VL + (vt * 16 + lr) * 128 +
                                     ((((ks * 4 + g) ^ (lr & 7)) & 7) << 4));
        cacc[0][vt] = __builtin_amdgcn_mfma_f32_16x16x32_bf16(pa0, vb, cacc[0][vt], 0, 0, 0);
        cacc[1][vt] = __builtin_amdgcn_mfma_f32_16x16x32_bf16(pa1, vb, cacc[1][vt], 0, 0, 0);
      }
    }
    __builtin_amdgcn_s_setprio(0);
  }

  // ---- epilogue: bf16 partials + (m raw, l) ----
#pragma unroll
  for (int rt = 0; rt < 2; rt++)
#pragma unroll
    for (int vt = 0; vt < 8; vt++)
#pragma unroll
      for (int r = 0; r < 4; r++) {
        int n = qrb + rt * 16 + g * 4 + r;
        size_t gn = (size_t)b * 4096 + n;
        float v = rt ? cacc[1][vt][r] : cacc[0][vt][r];
        pc[((size_t)sp * 16384 + gn) * 128 + vt * 16 + lr] = f2bf(v);
      }
  if (lr == 0) {
#pragma unroll
    for (int rt = 0; rt < 2; rt++)
#pragma unroll
      for (int r = 0; r < 4; r++) {
        int n = qrb + rt * 16 + g * 4 + r;
        size_t gn = (size_t)b * 4096 + n;
        ml[sp * 16384 + gn] = make_float2(rt ? m1[r] : m0[r], rt ? l1[r] : l0[r]);
      }
  }
}

// ---------------- K5: fused merge + output projection (MFMA) ---------------
// grid 256 = b(4) x nt(64, 64 n each). Merge nsp partials -> bf16 B-tile in
// LDS (XOR swizzle), MFMA with Ww bf16, write out[b][o][n] f32 + bias.
__launch_bounds__(256)
__global__ void k_mergeout(const unsigned short* __restrict__ pc,
                           const float2* __restrict__ ml,
                           const unsigned short* __restrict__ wwb,
                           const float* __restrict__ bw,
                           float* __restrict__ out, int nsp) {
  __shared__ float esc[8][64];
  __shared__ __align__(16) unsigned short Bl[64 * 128];
  const float C1 = 0.12754245f;
  int bid = blockIdx.x;
  int nt = bid & 63, b = bid >> 6;
  int n0 = nt * 64;
  size_t gnb = (size_t)b * 4096 + n0;
  int t = threadIdx.x;

  if (t < 64) {
    float m[8], l[8];
    for (int sp = 0; sp < nsp; sp++) {
      float2 v = ml[sp * 16384 + gnb + t];
      m[sp] = v.x; l[sp] = v.y;
    }
    float M = m[0];
    for (int sp = 1; sp < nsp; sp++) M = fmaxf(M, m[sp]);
    float L = 0.f, e[8];
    for (int sp = 0; sp < nsp; sp++) {
      e[sp] = __builtin_amdgcn_exp2f((m[sp] - M) * C1);
      L += l[sp] * e[sp];
    }
    float inv = 1.f / L;
    for (int sp = 0; sp < nsp; sp++) esc[sp][t] = e[sp] * inv;
  }
  __syncthreads();

  {  // merge 32 values per thread: n = t&63, v = (t>>6)*32 ..
    int n = t & 63, vs = t >> 6;
    float o[32] = {};
    for (int sp = 0; sp < nsp; sp++) {
      float es = esc[sp][n];
      const unsigned short* src = pc + ((size_t)sp * 16384 + gnb + n) * 128 + vs * 32;
#pragma unroll
      for (int c = 0; c < 4; c++) {
        short8 pv = *(const short8*)(src + c * 8);
#pragma unroll
        for (int j = 0; j < 8; j++) o[c * 8 + j] += es * bf2f((unsigned short)pv[j]);
      }
    }
    unsigned int* B32 = (unsigned int*)Bl;
#pragma unroll
    for (int jj = 0; jj < 16; jj++) {
      int v = vs * 32 + jj * 2;
      int kg = v >> 3;
      int kgp = (kg & 8) | ((kg ^ n) & 7);
      unsigned int pk = (unsigned int)f2bf(o[jj * 2]) |
                        ((unsigned int)f2bf(o[jj * 2 + 1]) << 16);
      B32[n * 64 + kgp * 4 + ((v & 7) >> 1)] = pk;
    }
  }
  __syncthreads();

  int wid = t >> 6, lane = t & 63, g = lane >> 4, lr = lane & 15;
  int o0 = wid * 64;
  short8 af[4][4];
#pragma unroll
  for (int ot = 0; ot < 4; ot++) {
    int o = o0 + ot * 16 + lr;
#pragma unroll
    for (int ks = 0; ks < 4; ks++)
      af[ot][ks] = *(const short8*)(wwb + (size_t)o * 128 + ks * 32 + g * 8);
  }
  f32x4 acc[4][4];
#pragma unroll
  for (int i = 0; i < 4; i++)
#pragma unroll
    for (int j = 0; j < 4; j++) acc[i][j] = (f32x4){0.f, 0.f, 0.f, 0.f};
#pragma unroll
  for (int nt2 = 0; nt2 < 4; nt2++) {
    short8 bfr[4];
#pragma unroll
    for (int ks = 0; ks < 4; ks++) {
      int kg = ks * 4 + g;
      int kgp = (kg & 8) | ((kg ^ lr) & 7);
      bfr[ks] = *(const short8*)(Bl + (nt2 * 16 + lr) * 128 + kgp * 8);
    }
#pragma unroll
    for (int ot = 0; ot < 4; ot++)
#pragma unroll
      for (int ks = 0; ks < 4; ks++)
        acc[ot][nt2] = __builtin_amdgcn_mfma_f32_16x16x32_bf16(af[ot][ks], bfr[ks],
                                                               acc[ot][nt2], 0, 0, 0);
  }
#pragma unroll
  for (int ot = 0; ot < 4; ot++)
#pragma unroll
    for (int r = 0; r < 4; r++) {
      int o = o0 + ot * 16 + g * 4 + r;
      float bias = bw[o];
#pragma unroll
      for (int nt2 = 0; nt2 < 4; nt2++)
        out[((size_t)(b * 256 + o)) * 4096 + n0 + nt2 * 16 + lr] = acc[ot][nt2][r] + bias;
    }
}

extern "C" void kernel_launch(void* const* d_in, const int* in_sizes, int n_in,
                              void* d_out, int out_size, void* d_ws, size_t ws_size,
                              hipStream_t stream) {
  const float* x  = (const float*)d_in[0];
  const float* Wk = (const float*)d_in[1];
  const float* bk = (const float*)d_in[2];
  const float* Wv = (const float*)d_in[3];
  const float* bv = (const float*)d_in[4];
  const float* Ww = (const float*)d_in[5];
  const float* bw = (const float*)d_in[6];
  const float* u  = (const float*)d_in[7];

  char* ws = (char*)d_ws;
  float* sig            = (float*)(ws + OFF_SIGMA);
  float2* ml            = (float2*)(ws + OFF_ML);
  unsigned short* qkT   = (unsigned short*)(ws + OFF_QKT);
  unsigned short* vbuf  = (unsigned short*)(ws + OFF_V);
  unsigned short* wwb   = (unsigned short*)(ws + OFF_WWB);
  float* xf             = (float*)(ws + OFF_XF);
  unsigned short* pc    = (unsigned short*)(ws + OFF_PC);
  float* out            = (float*)d_out;

  int nsp    = (ws_size >= NEED8) ? 8 : 4;
  int spbits = (nsp == 8) ? 3 : 2;

  k_maxpool<<<8192, 256, 0, stream>>>(x, xf);
  k_sigma<<<1, 256, 0, stream>>>(Wk, u, sig);
  k_prep<<<32, 256, 0, stream>>>(Ww, wwb);
  k_qkv<<<1024, 256, 0, stream>>>(xf, Wk, bk, Wv, bv, sig, qkT, vbuf);
  k_attn<<<128 * nsp, 256, 0, stream>>>(qkT, vbuf, pc, ml, nsp, spbits);
  k_mergeout<<<256, 256, 0, stream>>>(pc, ml, wwb, bw, out, nsp);
}